// Round 1
// baseline (594.665 us; speedup 1.0000x reference)
//
#include <hip/hip_runtime.h>
#include <hip/hip_bf16.h>

#define Bb 4
#define Ss 512
#define Hh 768
#define Dd 24
#define Mm 96
#define Oo 768

// ---------------------------------------------------------------------------
// Kernel A: Zj = H_j @ Wpj, Zi = H_i @ Wpi   (B*S rows, H=768 -> D=24)
// grid (B*S, 2), block 256
// ---------------------------------------------------------------------------
__global__ __launch_bounds__(256) void proj_kernel(
    const float* __restrict__ Hj, const float* __restrict__ Hi,
    const float* __restrict__ Wpj, const float* __restrict__ Wpi,
    float* __restrict__ Zj, float* __restrict__ Zi)
{
    const int row = blockIdx.x;
    const int which = blockIdx.y;
    const float* src = (which ? Hi : Hj) + (size_t)row * Hh;
    const float* W = which ? Wpi : Wpj;
    float* Z = which ? Zi : Zj;
    __shared__ float rowbuf[Hh];
    __shared__ float partial[8][Dd];
    const int tid = threadIdx.x;
    for (int i = tid; i < Hh; i += 256) rowbuf[i] = src[i];
    __syncthreads();
    if (tid < 192) {
        const int d = tid % Dd;
        const int c = tid / Dd;
        const int h0 = c * 96;
        float s = 0.f;
        #pragma unroll 4
        for (int h = h0; h < h0 + 96; ++h) s = fmaf(rowbuf[h], W[h * Dd + d], s);
        partial[c][d] = s;
    }
    __syncthreads();
    if (tid < Dd) {
        float s = 0.f;
        #pragma unroll
        for (int c = 0; c < 8; ++c) s += partial[c][tid];
        Z[(size_t)row * Dd + tid] = s;
    }
}

// ---------------------------------------------------------------------------
// Kernel B: per (b,p): logits over all q fused with softmax -> probs
// hid[q,m] = relu( sum_d Zi[q,d]*(Zj[p,d]*W1h[d,m] + W1i[d,m])
//                + sum_d |Zj[p,d]-Zi[q,d]|*W1d[d,m] + tj[p,m] + bs1[m] )
// logit[q] = hid[q,:]@ws2 + bs2 ; probs = softmax_q
// grid (B*S), block 256. Thread tile: 4 q x 8 m, q staged in 256-halves.
// ---------------------------------------------------------------------------
__global__ __launch_bounds__(256) void pair_kernel(
    const float* __restrict__ Zj, const float* __restrict__ Zi,
    const float* __restrict__ Ws1, const float* __restrict__ bs1,
    const float* __restrict__ ws2, const float* __restrict__ bs2p,
    const int* __restrict__ mask, float* __restrict__ probs)
{
    const int bp = blockIdx.x;
    const int b = bp >> 9;            // S = 512
    const int tid = threadIdx.x;

    __shared__ float zil[Dd][256];    // Zi transposed, half of q at a time (24 KB)
    __shared__ float wcomb[Dd][Mm];   // Zj[p,d]*W1h + W1i  (9 KB)
    __shared__ float w1d[Dd][Mm];     // (9 KB)
    __shared__ float rowadd[Mm];      // tj[p,:] + bs1
    __shared__ float ws2l[Mm];
    __shared__ float zjl[Dd];
    __shared__ float logitsl[Ss];
    __shared__ float red[256];

    if (tid < Dd) zjl[tid] = Zj[(size_t)bp * Dd + tid];
    __syncthreads();

    for (int idx = tid; idx < Dd * Mm; idx += 256) {
        const int d = idx / Mm, m = idx % Mm;
        wcomb[d][m] = zjl[d] * Ws1[(2 * Dd + d) * Mm + m] + Ws1[(Dd + d) * Mm + m];
        w1d[d][m]   = Ws1[(3 * Dd + d) * Mm + m];
    }
    if (tid < Mm) {
        float s = bs1[tid];
        #pragma unroll
        for (int d = 0; d < Dd; ++d) s = fmaf(zjl[d], Ws1[d * Mm + tid], s);
        rowadd[tid] = s;
        ws2l[tid] = ws2[tid];
    }
    for (int q = tid; q < Ss; q += 256) logitsl[q] = 0.f;

    const int qg = tid & 63;
    const int mg = tid >> 6;
    float plog[8];
    #pragma unroll
    for (int j = 0; j < 8; ++j) plog[j] = 0.f;

    const float* zib = Zi + (size_t)b * Ss * Dd;

    #pragma unroll
    for (int half = 0; half < 2; ++half) {
        __syncthreads();
        // stage 256 q of Zi, transposed to [d][q]
        for (int idx = tid; idx < 256 * Dd; idx += 256) {
            const int q = idx / Dd, d = idx % Dd;
            zil[d][q] = zib[half * 256 * Dd + idx];
        }
        __syncthreads();
        #pragma unroll
        for (int pass = 0; pass < 3; ++pass) {
            const int m0 = pass * 32 + mg * 8;
            float acc[4][8];
            #pragma unroll
            for (int j = 0; j < 4; ++j)
                #pragma unroll
                for (int i = 0; i < 8; ++i) acc[j][i] = 0.f;

            #pragma unroll 4
            for (int d = 0; d < Dd; ++d) {
                const float zjd = zjl[d];
                float zi[4], ad[4];
                #pragma unroll
                for (int j = 0; j < 4; ++j) {
                    zi[j] = zil[d][qg + 64 * j];
                    ad[j] = fabsf(zjd - zi[j]);
                }
                float wc[8], wd[8];
                *(float4*)&wc[0] = *(const float4*)&wcomb[d][m0];
                *(float4*)&wc[4] = *(const float4*)&wcomb[d][m0 + 4];
                *(float4*)&wd[0] = *(const float4*)&w1d[d][m0];
                *(float4*)&wd[4] = *(const float4*)&w1d[d][m0 + 4];
                #pragma unroll
                for (int i = 0; i < 8; ++i)
                    #pragma unroll
                    for (int j = 0; j < 4; ++j)
                        acc[j][i] = fmaf(zi[j], wc[i], fmaf(ad[j], wd[i], acc[j][i]));
            }
            #pragma unroll
            for (int i = 0; i < 8; ++i) {
                const float ra = rowadd[m0 + i];
                const float w2 = ws2l[m0 + i];
                #pragma unroll
                for (int j = 0; j < 4; ++j) {
                    const float hv = fmaxf(acc[j][i] + ra, 0.f);
                    plog[half * 4 + j] = fmaf(hv, w2, plog[half * 4 + j]);
                }
            }
        }
    }
    #pragma unroll
    for (int half = 0; half < 2; ++half)
        #pragma unroll
        for (int j = 0; j < 4; ++j)
            atomicAdd(&logitsl[half * 256 + qg + 64 * j], plog[half * 4 + j]);
    __syncthreads();

    // mask + bias, softmax over 512 q (2 per thread)
    const float bs2v = bs2p[0];
    const int* mrow = mask + (size_t)b * Ss;
    float l0 = logitsl[tid] + bs2v + (1.0f - (float)mrow[tid]) * (-3.402823466e+38f);
    float l1 = logitsl[tid + 256] + bs2v + (1.0f - (float)mrow[tid + 256]) * (-3.402823466e+38f);
    red[tid] = fmaxf(l0, l1);
    __syncthreads();
    for (int s = 128; s > 0; s >>= 1) {
        if (tid < s) red[tid] = fmaxf(red[tid], red[tid + s]);
        __syncthreads();
    }
    const float mx = red[0];
    __syncthreads();
    const float e0 = __expf(l0 - mx);
    const float e1 = __expf(l1 - mx);
    red[tid] = e0 + e1;
    __syncthreads();
    for (int s = 128; s > 0; s >>= 1) {
        if (tid < s) red[tid] += red[tid + s];
        __syncthreads();
    }
    const float inv = 1.0f / red[0];
    float* prow = probs + (size_t)bp * Ss;
    prow[tid] = e0 * inv;
    prow[tid + 256] = e1 * inv;
}

// ---------------------------------------------------------------------------
// Kernel C: ctx[b,p,h] = sum_q probs[b,p,q] * H_i[b,q,h]
// 64x64 output tile, K=512, grid (8,12,B), block 256 (16x16 threads, 4x4 regs)
// ---------------------------------------------------------------------------
__global__ __launch_bounds__(256) void ctx_kernel(
    const float* __restrict__ probs, const float* __restrict__ Hi,
    float* __restrict__ ctx)
{
    const int p0 = blockIdx.x * 64, h0 = blockIdx.y * 64;
    const int b = blockIdx.z;
    const int tid = threadIdx.x;
    const int tx = tid & 15, ty = tid >> 4;

    __shared__ float Ast[16][64];   // [k][p]
    __shared__ float Bs[16][64];    // [k][h]

    float acc[4][4];
    #pragma unroll
    for (int u = 0; u < 4; ++u)
        #pragma unroll
        for (int v = 0; v < 4; ++v) acc[u][v] = 0.f;

    const int ar = tid >> 2, ac = (tid & 3) * 4;
    const int br = tid >> 4, bc = (tid & 15) * 4;

    for (int kb = 0; kb < Ss; kb += 16) {
        const float4 av = *(const float4*)&probs[((size_t)b * Ss + p0 + ar) * Ss + kb + ac];
        const float4 bv = *(const float4*)&Hi[((size_t)b * Ss + kb + br) * Hh + h0 + bc];
        __syncthreads();
        Ast[ac + 0][ar] = av.x;
        Ast[ac + 1][ar] = av.y;
        Ast[ac + 2][ar] = av.z;
        Ast[ac + 3][ar] = av.w;
        *(float4*)&Bs[br][bc] = bv;
        __syncthreads();
        #pragma unroll
        for (int kk = 0; kk < 16; ++kk) {
            const float4 a4 = *(const float4*)&Ast[kk][ty * 4];
            const float4 b4 = *(const float4*)&Bs[kk][tx * 4];
            const float a[4] = {a4.x, a4.y, a4.z, a4.w};
            const float bbv[4] = {b4.x, b4.y, b4.z, b4.w};
            #pragma unroll
            for (int u = 0; u < 4; ++u)
                #pragma unroll
                for (int v = 0; v < 4; ++v)
                    acc[u][v] = fmaf(a[u], bbv[v], acc[u][v]);
        }
    }
    #pragma unroll
    for (int u = 0; u < 4; ++u) {
        float4 o = {acc[u][0], acc[u][1], acc[u][2], acc[u][3]};
        *(float4*)&ctx[((size_t)b * Ss + p0 + ty * 4 + u) * Hh + h0 + tx * 4] = o;
    }
}

// ---------------------------------------------------------------------------
// Kernel D: mhid = relu(ctx@Wc + Hj@Wj + (ctx.*Hj)@Wh + bv1)
// rows = B*S = 2048, cols = O = 768, K = 3*768 (3 A-sources)
// grid (32,12), block 256
// ---------------------------------------------------------------------------
__global__ __launch_bounds__(256) void mhid_kernel(
    const float* __restrict__ ctx, const float* __restrict__ Hj,
    const float* __restrict__ Wv1, const float* __restrict__ bv1,
    float* __restrict__ mhid)
{
    const int r0 = blockIdx.x * 64, o0 = blockIdx.y * 64;
    const int tid = threadIdx.x;
    const int tx = tid & 15, ty = tid >> 4;

    __shared__ float Ast[16][64];
    __shared__ float Bs[16][64];

    float acc[4][4];
    #pragma unroll
    for (int u = 0; u < 4; ++u)
        #pragma unroll
        for (int v = 0; v < 4; ++v) acc[u][v] = 0.f;

    const int ar = tid >> 2, ac = (tid & 3) * 4;
    const int br = tid >> 4, bc = (tid & 15) * 4;

    for (int s = 0; s < 3; ++s) {
        const float* A0 = (s == 1) ? Hj : ctx;
        for (int kb = 0; kb < Hh; kb += 16) {
            float4 av = *(const float4*)&A0[(size_t)(r0 + ar) * Hh + kb + ac];
            if (s == 2) {
                const float4 hv = *(const float4*)&Hj[(size_t)(r0 + ar) * Hh + kb + ac];
                av.x *= hv.x; av.y *= hv.y; av.z *= hv.z; av.w *= hv.w;
            }
            const float4 bv = *(const float4*)&Wv1[(size_t)(s * Hh + kb + br) * Oo + o0 + bc];
            __syncthreads();
            Ast[ac + 0][ar] = av.x;
            Ast[ac + 1][ar] = av.y;
            Ast[ac + 2][ar] = av.z;
            Ast[ac + 3][ar] = av.w;
            *(float4*)&Bs[br][bc] = bv;
            __syncthreads();
            #pragma unroll
            for (int kk = 0; kk < 16; ++kk) {
                const float4 a4 = *(const float4*)&Ast[kk][ty * 4];
                const float4 b4 = *(const float4*)&Bs[kk][tx * 4];
                const float a[4] = {a4.x, a4.y, a4.z, a4.w};
                const float bbv[4] = {b4.x, b4.y, b4.z, b4.w};
                #pragma unroll
                for (int u = 0; u < 4; ++u)
                    #pragma unroll
                    for (int v = 0; v < 4; ++v)
                        acc[u][v] = fmaf(a[u], bbv[v], acc[u][v]);
            }
        }
    }
    #pragma unroll
    for (int u = 0; u < 4; ++u) {
        float4 o;
        o.x = fmaxf(acc[u][0] + bv1[o0 + tx * 4 + 0], 0.f);
        o.y = fmaxf(acc[u][1] + bv1[o0 + tx * 4 + 1], 0.f);
        o.z = fmaxf(acc[u][2] + bv1[o0 + tx * 4 + 2], 0.f);
        o.w = fmaxf(acc[u][3] + bv1[o0 + tx * 4 + 3], 0.f);
        *(float4*)&mhid[(size_t)(r0 + ty * 4 + u) * Oo + o0 + tx * 4] = o;
    }
}

// ---------------------------------------------------------------------------
// Kernel E: out = alpha * (mhid @ Wv2 + bv2)
// rows = 2048, cols = H = 768, K = O = 768. grid (32,12), block 256
// ---------------------------------------------------------------------------
__global__ __launch_bounds__(256) void out_kernel(
    const float* __restrict__ mhid, const float* __restrict__ Wv2,
    const float* __restrict__ bv2, const float* __restrict__ alphap,
    float* __restrict__ out)
{
    const int r0 = blockIdx.x * 64, h0 = blockIdx.y * 64;
    const int tid = threadIdx.x;
    const int tx = tid & 15, ty = tid >> 4;

    __shared__ float Ast[16][64];
    __shared__ float Bs[16][64];

    float acc[4][4];
    #pragma unroll
    for (int u = 0; u < 4; ++u)
        #pragma unroll
        for (int v = 0; v < 4; ++v) acc[u][v] = 0.f;

    const int ar = tid >> 2, ac = (tid & 3) * 4;
    const int br = tid >> 4, bc = (tid & 15) * 4;

    for (int kb = 0; kb < Oo; kb += 16) {
        const float4 av = *(const float4*)&mhid[(size_t)(r0 + ar) * Oo + kb + ac];
        const float4 bv = *(const float4*)&Wv2[(size_t)(kb + br) * Hh + h0 + bc];
        __syncthreads();
        Ast[ac + 0][ar] = av.x;
        Ast[ac + 1][ar] = av.y;
        Ast[ac + 2][ar] = av.z;
        Ast[ac + 3][ar] = av.w;
        *(float4*)&Bs[br][bc] = bv;
        __syncthreads();
        #pragma unroll
        for (int kk = 0; kk < 16; ++kk) {
            const float4 a4 = *(const float4*)&Ast[kk][ty * 4];
            const float4 b4 = *(const float4*)&Bs[kk][tx * 4];
            const float a[4] = {a4.x, a4.y, a4.z, a4.w};
            const float bbv[4] = {b4.x, b4.y, b4.z, b4.w};
            #pragma unroll
            for (int u = 0; u < 4; ++u)
                #pragma unroll
                for (int v = 0; v < 4; ++v)
                    acc[u][v] = fmaf(a[u], bbv[v], acc[u][v]);
        }
    }
    const float al = alphap[0];
    #pragma unroll
    for (int u = 0; u < 4; ++u) {
        float4 o;
        o.x = al * (acc[u][0] + bv2[h0 + tx * 4 + 0]);
        o.y = al * (acc[u][1] + bv2[h0 + tx * 4 + 1]);
        o.z = al * (acc[u][2] + bv2[h0 + tx * 4 + 2]);
        o.w = al * (acc[u][3] + bv2[h0 + tx * 4 + 3]);
        *(float4*)&out[(size_t)(r0 + ty * 4 + u) * Hh + h0 + tx * 4] = o;
    }
}

// ---------------------------------------------------------------------------
extern "C" void kernel_launch(void* const* d_in, const int* in_sizes, int n_in,
                              void* d_out, int out_size, void* d_ws, size_t ws_size,
                              hipStream_t stream)
{
    const float* Hj  = (const float*)d_in[0];
    const float* Hi  = (const float*)d_in[1];
    const float* Wpj = (const float*)d_in[2];
    const float* Wpi = (const float*)d_in[3];
    const float* Ws1 = (const float*)d_in[4];
    const float* bs1 = (const float*)d_in[5];
    const float* ws2 = (const float*)d_in[6];
    const float* bs2 = (const float*)d_in[7];
    const float* Wv1 = (const float*)d_in[8];
    const float* bv1 = (const float*)d_in[9];
    const float* Wv2 = (const float*)d_in[10];
    const float* bv2 = (const float*)d_in[11];
    const float* alpha = (const float*)d_in[12];
    const int* mask  = (const int*)d_in[13];

    float* ws = (float*)d_ws;
    float* Zj    = ws;                                   // B*S*D
    float* Zi    = Zj + (size_t)Bb * Ss * Dd;            // B*S*D
    float* probs = Zi + (size_t)Bb * Ss * Dd;            // B*S*S
    float* ctx   = probs + (size_t)Bb * Ss * Ss;         // B*S*H
    float* mhid  = ctx + (size_t)Bb * Ss * Hh;           // B*S*O
    // total: 4,292,608 floats = 17.2 MB

    proj_kernel<<<dim3(Bb * Ss, 2), 256, 0, stream>>>(Hj, Hi, Wpj, Wpi, Zj, Zi);
    pair_kernel<<<dim3(Bb * Ss), 256, 0, stream>>>(Zj, Zi, Ws1, bs1, ws2, bs2, mask, probs);
    ctx_kernel<<<dim3(Ss / 64, Hh / 64, Bb), 256, 0, stream>>>(probs, Hi, ctx);
    mhid_kernel<<<dim3((Bb * Ss) / 64, Oo / 64), 256, 0, stream>>>(ctx, Hj, Wv1, bv1, mhid);
    out_kernel<<<dim3((Bb * Ss) / 64, Hh / 64), 256, 0, stream>>>(mhid, Wv2, bv2, alpha, (float*)d_out);
}

// Round 2
// 386.480 us; speedup vs baseline: 1.5387x; 1.5387x over previous
//
#include <hip/hip_runtime.h>
#include <hip/hip_bf16.h>

#define Bb 4
#define Ss 512
#define Hh 768
#define Dd 24
#define Mm 96
#define Oo 768

typedef __bf16 bf16x8 __attribute__((ext_vector_type(8)));
typedef float f32x4 __attribute__((ext_vector_type(4)));

// ---------------------------------------------------------------------------
// Kernel A: Zj = H_j @ Wpj, Zi = H_i @ Wpi   (B*S rows, H=768 -> D=24)
// ---------------------------------------------------------------------------
__global__ __launch_bounds__(256) void proj_kernel(
    const float* __restrict__ Hj, const float* __restrict__ Hi,
    const float* __restrict__ Wpj, const float* __restrict__ Wpi,
    float* __restrict__ Zj, float* __restrict__ Zi)
{
    const int row = blockIdx.x;
    const int which = blockIdx.y;
    const float* src = (which ? Hi : Hj) + (size_t)row * Hh;
    const float* W = which ? Wpi : Wpj;
    float* Z = which ? Zi : Zj;
    __shared__ float rowbuf[Hh];
    __shared__ float partial[8][Dd];
    const int tid = threadIdx.x;
    for (int i = tid; i < Hh; i += 256) rowbuf[i] = src[i];
    __syncthreads();
    if (tid < 192) {
        const int d = tid % Dd;
        const int c = tid / Dd;
        const int h0 = c * 96;
        float s = 0.f;
        #pragma unroll 4
        for (int h = h0; h < h0 + 96; ++h) s = fmaf(rowbuf[h], W[h * Dd + d], s);
        partial[c][d] = s;
    }
    __syncthreads();
    if (tid < Dd) {
        float s = 0.f;
        #pragma unroll
        for (int c = 0; c < 8; ++c) s += partial[c][tid];
        Z[(size_t)row * Dd + tid] = s;
    }
}

// ---------------------------------------------------------------------------
// Kernel B (MFMA): per (b,p) block computes logits over all 512 q + softmax.
// GEMM view per p:  hid[q][m] = relu( A_p[q][0:64] @ B_p[0:64][m] )
//   A k 0..23  = Zi[q][d]            B = Zj[p,d]*W1h[d][m] + W1i[d][m]
//   A k 24     = 1.0                 B = tj[p][m] + bs1[m]  (bias fold)
//   A k 32..55 = |Zj[p,d]-Zi[q,d]|   B = W1d[d][m]
// mfma_f32_16x16x32_bf16, A-frags built in registers straight from global.
// logits[q] = hid@ws2 via shfl-reduce; softmax in-block.
// ---------------------------------------------------------------------------
__global__ __launch_bounds__(256) void pair_kernel(
    const float* __restrict__ Zj, const float* __restrict__ Zi,
    const float* __restrict__ Ws1, const float* __restrict__ bs1,
    const float* __restrict__ ws2, const float* __restrict__ bs2p,
    const int* __restrict__ mask, float* __restrict__ probs)
{
    const int bp = blockIdx.x;
    const int b  = bp >> 9;              // S = 512
    const int tid  = threadIdx.x;
    const int lane = tid & 63;
    const int wid  = tid >> 6;
    const int col  = lane & 15;          // A: q-row / B,D: m-col
    const int g    = lane >> 4;          // k-quad

    __shared__ float zjall[Dd];
    __shared__ float rowadd[Mm];
    __shared__ float logitsl[Ss];
    __shared__ float red[8];

    if (tid < Dd) zjall[tid] = Zj[(size_t)bp * Dd + tid];
    __syncthreads();
    if (tid < Mm) {
        float s = bs1[tid];
        #pragma unroll
        for (int d = 0; d < Dd; ++d) s = fmaf(zjall[d], Ws1[d * Mm + tid], s);
        rowadd[tid] = s;                 // tj[p,m] + bs1[m]
    }
    __syncthreads();

    // per-lane zj slice for its 8 k's
    float zj8[8];
    if (g < 3) {
        const float* zr = Zj + (size_t)bp * Dd + g * 8;
        const float4 u = *(const float4*)zr;
        const float4 v = *(const float4*)(zr + 4);
        zj8[0]=u.x; zj8[1]=u.y; zj8[2]=u.z; zj8[3]=u.w;
        zj8[4]=v.x; zj8[5]=v.y; zj8[6]=v.z; zj8[7]=v.w;
    } else {
        #pragma unroll
        for (int j = 0; j < 8; ++j) zj8[j] = 0.f;
    }

    // B-fragments (weights), kept in registers, reused across all 32 M-tiles
    bf16x8 bw[6][2];
    float ws2r[6];
    #pragma unroll
    for (int n = 0; n < 6; ++n) {
        const int m = n * 16 + col;
        ws2r[n] = ws2[m];
        bf16x8 b0, b1;
        if (g < 3) {
            #pragma unroll
            for (int j = 0; j < 8; ++j) {
                const int d = g * 8 + j;
                b0[j] = (__bf16)(fmaf(zj8[j], Ws1[(2 * Dd + d) * Mm + m],
                                      Ws1[(Dd + d) * Mm + m]));
                b1[j] = (__bf16)(Ws1[(3 * Dd + d) * Mm + m]);
            }
        } else {
            #pragma unroll
            for (int j = 0; j < 8; ++j) { b0[j] = (__bf16)0.f; b1[j] = (__bf16)0.f; }
            b0[0] = (__bf16)rowadd[m];   // k=24 row: bias (pairs with A==1.0)
        }
        bw[n][0] = b0; bw[n][1] = b1;
    }

    const float* zib = Zi + (size_t)b * Ss * Dd;

    #pragma unroll 2
    for (int t = 0; t < 8; ++t) {
        const int q0 = wid * 128 + t * 16;
        bf16x8 a0, a1;
        if (g < 3) {
            const float* zr = zib + (size_t)(q0 + col) * Dd + g * 8;
            const float4 u = *(const float4*)zr;
            const float4 v = *(const float4*)(zr + 4);
            a0[0]=(__bf16)u.x; a0[1]=(__bf16)u.y; a0[2]=(__bf16)u.z; a0[3]=(__bf16)u.w;
            a0[4]=(__bf16)v.x; a0[5]=(__bf16)v.y; a0[6]=(__bf16)v.z; a0[7]=(__bf16)v.w;
            a1[0]=(__bf16)fabsf(zj8[0]-u.x); a1[1]=(__bf16)fabsf(zj8[1]-u.y);
            a1[2]=(__bf16)fabsf(zj8[2]-u.z); a1[3]=(__bf16)fabsf(zj8[3]-u.w);
            a1[4]=(__bf16)fabsf(zj8[4]-v.x); a1[5]=(__bf16)fabsf(zj8[5]-v.y);
            a1[6]=(__bf16)fabsf(zj8[6]-v.z); a1[7]=(__bf16)fabsf(zj8[7]-v.w);
        } else {
            #pragma unroll
            for (int j = 0; j < 8; ++j) { a0[j] = (__bf16)0.f; a1[j] = (__bf16)0.f; }
            a0[0] = (__bf16)1.0f;        // k=24 unit column -> bias row
        }

        f32x4 acc[6];
        #pragma unroll
        for (int n = 0; n < 6; ++n) acc[n] = (f32x4){0.f, 0.f, 0.f, 0.f};
        #pragma unroll
        for (int n = 0; n < 6; ++n) {
            acc[n] = __builtin_amdgcn_mfma_f32_16x16x32_bf16(a0, bw[n][0], acc[n], 0, 0, 0);
            acc[n] = __builtin_amdgcn_mfma_f32_16x16x32_bf16(a1, bw[n][1], acc[n], 0, 0, 0);
        }

        // logits: relu(hid) @ ws2, reduce over m (6 n-tiles in regs + 16 cols across lanes)
        float lsum[4] = {0.f, 0.f, 0.f, 0.f};
        #pragma unroll
        for (int n = 0; n < 6; ++n)
            #pragma unroll
            for (int r = 0; r < 4; ++r)
                lsum[r] = fmaf(fmaxf(acc[n][r], 0.f), ws2r[n], lsum[r]);
        #pragma unroll
        for (int off = 1; off <= 8; off <<= 1) {
            #pragma unroll
            for (int r = 0; r < 4; ++r) lsum[r] += __shfl_xor(lsum[r], off);
        }
        if (col == 0) {
            float4 o = {lsum[0], lsum[1], lsum[2], lsum[3]};
            *(float4*)&logitsl[q0 + g * 4] = o;   // rows q0+g*4 .. +3
        }
    }
    __syncthreads();

    // mask + bias + softmax over 512 q (2 per thread), shfl-based reductions
    const float bs2v = bs2p[0];
    const int* mrow = mask + (size_t)b * Ss;
    float l0 = logitsl[tid]       + bs2v + (1.0f - (float)mrow[tid])       * (-3.402823466e+38f);
    float l1 = logitsl[tid + 256] + bs2v + (1.0f - (float)mrow[tid + 256]) * (-3.402823466e+38f);
    float vmax = fmaxf(l0, l1);
    #pragma unroll
    for (int off = 32; off > 0; off >>= 1) vmax = fmaxf(vmax, __shfl_xor(vmax, off));
    if (lane == 0) red[wid] = vmax;
    __syncthreads();
    const float mx = fmaxf(fmaxf(red[0], red[1]), fmaxf(red[2], red[3]));
    const float e0 = __expf(l0 - mx);
    const float e1 = __expf(l1 - mx);
    float vs = e0 + e1;
    #pragma unroll
    for (int off = 32; off > 0; off >>= 1) vs += __shfl_xor(vs, off);
    if (lane == 0) red[4 + wid] = vs;
    __syncthreads();
    const float inv = 1.0f / (red[4] + red[5] + red[6] + red[7]);
    float* prow = probs + (size_t)bp * Ss;
    prow[tid] = e0 * inv;
    prow[tid + 256] = e1 * inv;
}

// ---------------------------------------------------------------------------
// Kernel C: ctx[b,p,h] = sum_q probs[b,p,q] * H_i[b,q,h]
// ---------------------------------------------------------------------------
__global__ __launch_bounds__(256) void ctx_kernel(
    const float* __restrict__ probs, const float* __restrict__ Hi,
    float* __restrict__ ctx)
{
    const int p0 = blockIdx.x * 64, h0 = blockIdx.y * 64;
    const int b = blockIdx.z;
    const int tid = threadIdx.x;
    const int tx = tid & 15, ty = tid >> 4;

    __shared__ float Ast[16][64];
    __shared__ float Bs[16][64];

    float acc[4][4];
    #pragma unroll
    for (int u = 0; u < 4; ++u)
        #pragma unroll
        for (int v = 0; v < 4; ++v) acc[u][v] = 0.f;

    const int ar = tid >> 2, ac = (tid & 3) * 4;
    const int br = tid >> 4, bc = (tid & 15) * 4;

    for (int kb = 0; kb < Ss; kb += 16) {
        const float4 av = *(const float4*)&probs[((size_t)b * Ss + p0 + ar) * Ss + kb + ac];
        const float4 bv = *(const float4*)&Hi[((size_t)b * Ss + kb + br) * Hh + h0 + bc];
        __syncthreads();
        Ast[ac + 0][ar] = av.x;
        Ast[ac + 1][ar] = av.y;
        Ast[ac + 2][ar] = av.z;
        Ast[ac + 3][ar] = av.w;
        *(float4*)&Bs[br][bc] = bv;
        __syncthreads();
        #pragma unroll
        for (int kk = 0; kk < 16; ++kk) {
            const float4 a4 = *(const float4*)&Ast[kk][ty * 4];
            const float4 b4 = *(const float4*)&Bs[kk][tx * 4];
            const float a[4] = {a4.x, a4.y, a4.z, a4.w};
            const float bbv[4] = {b4.x, b4.y, b4.z, b4.w};
            #pragma unroll
            for (int u = 0; u < 4; ++u)
                #pragma unroll
                for (int v = 0; v < 4; ++v)
                    acc[u][v] = fmaf(a[u], bbv[v], acc[u][v]);
        }
    }
    #pragma unroll
    for (int u = 0; u < 4; ++u) {
        float4 o = {acc[u][0], acc[u][1], acc[u][2], acc[u][3]};
        *(float4*)&ctx[((size_t)b * Ss + p0 + ty * 4 + u) * Hh + h0 + tx * 4] = o;
    }
}

// ---------------------------------------------------------------------------
// Kernel D: mhid = relu(ctx@Wc + Hj@Wj + (ctx.*Hj)@Wh + bv1)
// ---------------------------------------------------------------------------
__global__ __launch_bounds__(256) void mhid_kernel(
    const float* __restrict__ ctx, const float* __restrict__ Hj,
    const float* __restrict__ Wv1, const float* __restrict__ bv1,
    float* __restrict__ mhid)
{
    const int r0 = blockIdx.x * 64, o0 = blockIdx.y * 64;
    const int tid = threadIdx.x;
    const int tx = tid & 15, ty = tid >> 4;

    __shared__ float Ast[16][64];
    __shared__ float Bs[16][64];

    float acc[4][4];
    #pragma unroll
    for (int u = 0; u < 4; ++u)
        #pragma unroll
        for (int v = 0; v < 4; ++v) acc[u][v] = 0.f;

    const int ar = tid >> 2, ac = (tid & 3) * 4;
    const int br = tid >> 4, bc = (tid & 15) * 4;

    for (int s = 0; s < 3; ++s) {
        const float* A0 = (s == 1) ? Hj : ctx;
        for (int kb = 0; kb < Hh; kb += 16) {
            float4 av = *(const float4*)&A0[(size_t)(r0 + ar) * Hh + kb + ac];
            if (s == 2) {
                const float4 hv = *(const float4*)&Hj[(size_t)(r0 + ar) * Hh + kb + ac];
                av.x *= hv.x; av.y *= hv.y; av.z *= hv.z; av.w *= hv.w;
            }
            const float4 bv = *(const float4*)&Wv1[(size_t)(s * Hh + kb + br) * Oo + o0 + bc];
            __syncthreads();
            Ast[ac + 0][ar] = av.x;
            Ast[ac + 1][ar] = av.y;
            Ast[ac + 2][ar] = av.z;
            Ast[ac + 3][ar] = av.w;
            *(float4*)&Bs[br][bc] = bv;
            __syncthreads();
            #pragma unroll
            for (int kk = 0; kk < 16; ++kk) {
                const float4 a4 = *(const float4*)&Ast[kk][ty * 4];
                const float4 b4 = *(const float4*)&Bs[kk][tx * 4];
                const float a[4] = {a4.x, a4.y, a4.z, a4.w};
                const float bbv[4] = {b4.x, b4.y, b4.z, b4.w};
                #pragma unroll
                for (int u = 0; u < 4; ++u)
                    #pragma unroll
                    for (int v = 0; v < 4; ++v)
                        acc[u][v] = fmaf(a[u], bbv[v], acc[u][v]);
            }
        }
    }
    #pragma unroll
    for (int u = 0; u < 4; ++u) {
        float4 o;
        o.x = fmaxf(acc[u][0] + bv1[o0 + tx * 4 + 0], 0.f);
        o.y = fmaxf(acc[u][1] + bv1[o0 + tx * 4 + 1], 0.f);
        o.z = fmaxf(acc[u][2] + bv1[o0 + tx * 4 + 2], 0.f);
        o.w = fmaxf(acc[u][3] + bv1[o0 + tx * 4 + 3], 0.f);
        *(float4*)&mhid[(size_t)(r0 + ty * 4 + u) * Oo + o0 + tx * 4] = o;
    }
}

// ---------------------------------------------------------------------------
// Kernel E: out = alpha * (mhid @ Wv2 + bv2)
// ---------------------------------------------------------------------------
__global__ __launch_bounds__(256) void out_kernel(
    const float* __restrict__ mhid, const float* __restrict__ Wv2,
    const float* __restrict__ bv2, const float* __restrict__ alphap,
    float* __restrict__ out)
{
    const int r0 = blockIdx.x * 64, h0 = blockIdx.y * 64;
    const int tid = threadIdx.x;
    const int tx = tid & 15, ty = tid >> 4;

    __shared__ float Ast[16][64];
    __shared__ float Bs[16][64];

    float acc[4][4];
    #pragma unroll
    for (int u = 0; u < 4; ++u)
        #pragma unroll
        for (int v = 0; v < 4; ++v) acc[u][v] = 0.f;

    const int ar = tid >> 2, ac = (tid & 3) * 4;
    const int br = tid >> 4, bc = (tid & 15) * 4;

    for (int kb = 0; kb < Oo; kb += 16) {
        const float4 av = *(const float4*)&mhid[(size_t)(r0 + ar) * Oo + kb + ac];
        const float4 bv = *(const float4*)&Wv2[(size_t)(kb + br) * Hh + h0 + bc];
        __syncthreads();
        Ast[ac + 0][ar] = av.x;
        Ast[ac + 1][ar] = av.y;
        Ast[ac + 2][ar] = av.z;
        Ast[ac + 3][ar] = av.w;
        *(float4*)&Bs[br][bc] = bv;
        __syncthreads();
        #pragma unroll
        for (int kk = 0; kk < 16; ++kk) {
            const float4 a4 = *(const float4*)&Ast[kk][ty * 4];
            const float4 b4 = *(const float4*)&Bs[kk][tx * 4];
            const float a[4] = {a4.x, a4.y, a4.z, a4.w};
            const float bbv[4] = {b4.x, b4.y, b4.z, b4.w};
            #pragma unroll
            for (int u = 0; u < 4; ++u)
                #pragma unroll
                for (int v = 0; v < 4; ++v)
                    acc[u][v] = fmaf(a[u], bbv[v], acc[u][v]);
        }
    }
    const float al = alphap[0];
    #pragma unroll
    for (int u = 0; u < 4; ++u) {
        float4 o;
        o.x = al * (acc[u][0] + bv2[h0 + tx * 4 + 0]);
        o.y = al * (acc[u][1] + bv2[h0 + tx * 4 + 1]);
        o.z = al * (acc[u][2] + bv2[h0 + tx * 4 + 2]);
        o.w = al * (acc[u][3] + bv2[h0 + tx * 4 + 3]);
        *(float4*)&out[(size_t)(r0 + ty * 4 + u) * Hh + h0 + tx * 4] = o;
    }
}

// ---------------------------------------------------------------------------
extern "C" void kernel_launch(void* const* d_in, const int* in_sizes, int n_in,
                              void* d_out, int out_size, void* d_ws, size_t ws_size,
                              hipStream_t stream)
{
    const float* Hj  = (const float*)d_in[0];
    const float* Hi  = (const float*)d_in[1];
    const float* Wpj = (const float*)d_in[2];
    const float* Wpi = (const float*)d_in[3];
    const float* Ws1 = (const float*)d_in[4];
    const float* bs1 = (const float*)d_in[5];
    const float* ws2 = (const float*)d_in[6];
    const float* bs2 = (const float*)d_in[7];
    const float* Wv1 = (const float*)d_in[8];
    const float* bv1 = (const float*)d_in[9];
    const float* Wv2 = (const float*)d_in[10];
    const float* bv2 = (const float*)d_in[11];
    const float* alpha = (const float*)d_in[12];
    const int* mask  = (const int*)d_in[13];

    float* ws = (float*)d_ws;
    float* Zj    = ws;                                   // B*S*D
    float* Zi    = Zj + (size_t)Bb * Ss * Dd;            // B*S*D
    float* probs = Zi + (size_t)Bb * Ss * Dd;            // B*S*S
    float* ctx   = probs + (size_t)Bb * Ss * Ss;         // B*S*H
    float* mhid  = ctx + (size_t)Bb * Ss * Hh;           // B*S*O

    proj_kernel<<<dim3(Bb * Ss, 2), 256, 0, stream>>>(Hj, Hi, Wpj, Wpi, Zj, Zi);
    pair_kernel<<<dim3(Bb * Ss), 256, 0, stream>>>(Zj, Zi, Ws1, bs1, ws2, bs2, mask, probs);
    ctx_kernel<<<dim3(Ss / 64, Hh / 64, Bb), 256, 0, stream>>>(probs, Hi, ctx);
    mhid_kernel<<<dim3((Bb * Ss) / 64, Oo / 64), 256, 0, stream>>>(ctx, Hj, Wv1, bv1, mhid);
    out_kernel<<<dim3((Bb * Ss) / 64, Hh / 64), 256, 0, stream>>>(mhid, Wv2, bv2, alpha, (float*)d_out);
}

// Round 3
// 265.255 us; speedup vs baseline: 2.2419x; 1.4570x over previous
//
#include <hip/hip_runtime.h>
#include <hip/hip_bf16.h>

#define Bb 4
#define Ss 512
#define Hh 768
#define Dd 24
#define Mm 96
#define Oo 768

typedef __bf16 bf16x8 __attribute__((ext_vector_type(8)));
typedef float f32x4 __attribute__((ext_vector_type(4)));

// ---------------------------------------------------------------------------
// Kernel A: Zj = H_j @ Wpj, Zi = H_i @ Wpi   (B*S rows, H=768 -> D=24)
// ---------------------------------------------------------------------------
__global__ __launch_bounds__(256) void proj_kernel(
    const float* __restrict__ Hj, const float* __restrict__ Hi,
    const float* __restrict__ Wpj, const float* __restrict__ Wpi,
    float* __restrict__ Zj, float* __restrict__ Zi)
{
    const int row = blockIdx.x;
    const int which = blockIdx.y;
    const float* src = (which ? Hi : Hj) + (size_t)row * Hh;
    const float* W = which ? Wpi : Wpj;
    float* Z = which ? Zi : Zj;
    __shared__ float rowbuf[Hh];
    __shared__ float partial[8][Dd];
    const int tid = threadIdx.x;
    for (int i = tid; i < Hh; i += 256) rowbuf[i] = src[i];
    __syncthreads();
    if (tid < 192) {
        const int d = tid % Dd;
        const int c = tid / Dd;
        const int h0 = c * 96;
        float s = 0.f;
        #pragma unroll 4
        for (int h = h0; h < h0 + 96; ++h) s = fmaf(rowbuf[h], W[h * Dd + d], s);
        partial[c][d] = s;
    }
    __syncthreads();
    if (tid < Dd) {
        float s = 0.f;
        #pragma unroll
        for (int c = 0; c < 8; ++c) s += partial[c][tid];
        Z[(size_t)row * Dd + tid] = s;
    }
}

// ---------------------------------------------------------------------------
// Transpose + fp32->bf16:  dst[c][r] = bf16(src[r][c]),  tiles 32x32
// grid (C/32, R/32, nbatch), block 256 (32x8)
// ---------------------------------------------------------------------------
__global__ __launch_bounds__(256) void transpose_bf16_kernel(
    const float* __restrict__ src, __bf16* __restrict__ dst,
    int R, int C, long sbatch, long dbatch)
{
    const float* s = src + (size_t)blockIdx.z * sbatch;
    __bf16* d = dst + (size_t)blockIdx.z * dbatch;
    __shared__ float t[32][33];
    const int x = threadIdx.x & 31, y = threadIdx.x >> 5;
    const int c0 = blockIdx.x * 32, r0 = blockIdx.y * 32;
    #pragma unroll
    for (int i = 0; i < 4; ++i)
        t[y + 8 * i][x] = s[(size_t)(r0 + y + 8 * i) * C + c0 + x];
    __syncthreads();
    #pragma unroll
    for (int i = 0; i < 4; ++i)
        d[(size_t)(c0 + y + 8 * i) * R + r0 + x] = (__bf16)t[x][y + 8 * i];
}

// ---------------------------------------------------------------------------
// Kernel B (MFMA): per (b,p) block: logits over all 512 q + softmax -> bf16 probs
// ---------------------------------------------------------------------------
__global__ __launch_bounds__(256) void pair_kernel(
    const float* __restrict__ Zj, const float* __restrict__ Zi,
    const float* __restrict__ Ws1, const float* __restrict__ bs1,
    const float* __restrict__ ws2, const float* __restrict__ bs2p,
    const int* __restrict__ mask, __bf16* __restrict__ probs)
{
    const int bp = blockIdx.x;
    const int b  = bp >> 9;              // S = 512
    const int tid  = threadIdx.x;
    const int lane = tid & 63;
    const int wid  = tid >> 6;
    const int col  = lane & 15;
    const int g    = lane >> 4;

    __shared__ float zjall[Dd];
    __shared__ float rowadd[Mm];
    __shared__ float logitsl[Ss];
    __shared__ float red[8];

    if (tid < Dd) zjall[tid] = Zj[(size_t)bp * Dd + tid];
    __syncthreads();
    if (tid < Mm) {
        float s = bs1[tid];
        #pragma unroll
        for (int d = 0; d < Dd; ++d) s = fmaf(zjall[d], Ws1[d * Mm + tid], s);
        rowadd[tid] = s;
    }
    __syncthreads();

    float zj8[8];
    if (g < 3) {
        const float* zr = Zj + (size_t)bp * Dd + g * 8;
        const float4 u = *(const float4*)zr;
        const float4 v = *(const float4*)(zr + 4);
        zj8[0]=u.x; zj8[1]=u.y; zj8[2]=u.z; zj8[3]=u.w;
        zj8[4]=v.x; zj8[5]=v.y; zj8[6]=v.z; zj8[7]=v.w;
    } else {
        #pragma unroll
        for (int j = 0; j < 8; ++j) zj8[j] = 0.f;
    }

    bf16x8 bw[6][2];
    float ws2r[6];
    #pragma unroll
    for (int n = 0; n < 6; ++n) {
        const int m = n * 16 + col;
        ws2r[n] = ws2[m];
        bf16x8 b0, b1;
        if (g < 3) {
            #pragma unroll
            for (int j = 0; j < 8; ++j) {
                const int d = g * 8 + j;
                b0[j] = (__bf16)(fmaf(zj8[j], Ws1[(2 * Dd + d) * Mm + m],
                                      Ws1[(Dd + d) * Mm + m]));
                b1[j] = (__bf16)(Ws1[(3 * Dd + d) * Mm + m]);
            }
        } else {
            #pragma unroll
            for (int j = 0; j < 8; ++j) { b0[j] = (__bf16)0.f; b1[j] = (__bf16)0.f; }
            b0[0] = (__bf16)rowadd[m];
        }
        bw[n][0] = b0; bw[n][1] = b1;
    }

    const float* zib = Zi + (size_t)b * Ss * Dd;

    #pragma unroll 2
    for (int t = 0; t < 8; ++t) {
        const int q0 = wid * 128 + t * 16;
        bf16x8 a0, a1;
        if (g < 3) {
            const float* zr = zib + (size_t)(q0 + col) * Dd + g * 8;
            const float4 u = *(const float4*)zr;
            const float4 v = *(const float4*)(zr + 4);
            a0[0]=(__bf16)u.x; a0[1]=(__bf16)u.y; a0[2]=(__bf16)u.z; a0[3]=(__bf16)u.w;
            a0[4]=(__bf16)v.x; a0[5]=(__bf16)v.y; a0[6]=(__bf16)v.z; a0[7]=(__bf16)v.w;
            a1[0]=(__bf16)fabsf(zj8[0]-u.x); a1[1]=(__bf16)fabsf(zj8[1]-u.y);
            a1[2]=(__bf16)fabsf(zj8[2]-u.z); a1[3]=(__bf16)fabsf(zj8[3]-u.w);
            a1[4]=(__bf16)fabsf(zj8[4]-v.x); a1[5]=(__bf16)fabsf(zj8[5]-v.y);
            a1[6]=(__bf16)fabsf(zj8[6]-v.z); a1[7]=(__bf16)fabsf(zj8[7]-v.w);
        } else {
            #pragma unroll
            for (int j = 0; j < 8; ++j) { a0[j] = (__bf16)0.f; a1[j] = (__bf16)0.f; }
            a0[0] = (__bf16)1.0f;
        }

        f32x4 acc[6];
        #pragma unroll
        for (int n = 0; n < 6; ++n) acc[n] = (f32x4){0.f, 0.f, 0.f, 0.f};
        #pragma unroll
        for (int n = 0; n < 6; ++n) {
            acc[n] = __builtin_amdgcn_mfma_f32_16x16x32_bf16(a0, bw[n][0], acc[n], 0, 0, 0);
            acc[n] = __builtin_amdgcn_mfma_f32_16x16x32_bf16(a1, bw[n][1], acc[n], 0, 0, 0);
        }

        float lsum[4] = {0.f, 0.f, 0.f, 0.f};
        #pragma unroll
        for (int n = 0; n < 6; ++n)
            #pragma unroll
            for (int r = 0; r < 4; ++r)
                lsum[r] = fmaf(fmaxf(acc[n][r], 0.f), ws2r[n], lsum[r]);
        #pragma unroll
        for (int off = 1; off <= 8; off <<= 1) {
            #pragma unroll
            for (int r = 0; r < 4; ++r) lsum[r] += __shfl_xor(lsum[r], off);
        }
        if (col == 0) {
            float4 o = {lsum[0], lsum[1], lsum[2], lsum[3]};
            *(float4*)&logitsl[q0 + g * 4] = o;
        }
    }
    __syncthreads();

    const float bs2v = bs2p[0];
    const int* mrow = mask + (size_t)b * Ss;
    float l0 = logitsl[tid]       + bs2v + (1.0f - (float)mrow[tid])       * (-3.402823466e+38f);
    float l1 = logitsl[tid + 256] + bs2v + (1.0f - (float)mrow[tid + 256]) * (-3.402823466e+38f);
    float vmax = fmaxf(l0, l1);
    #pragma unroll
    for (int off = 32; off > 0; off >>= 1) vmax = fmaxf(vmax, __shfl_xor(vmax, off));
    if (lane == 0) red[wid] = vmax;
    __syncthreads();
    const float mx = fmaxf(fmaxf(red[0], red[1]), fmaxf(red[2], red[3]));
    const float e0 = __expf(l0 - mx);
    const float e1 = __expf(l1 - mx);
    float vs = e0 + e1;
    #pragma unroll
    for (int off = 32; off > 0; off >>= 1) vs += __shfl_xor(vs, off);
    if (lane == 0) red[4 + wid] = vs;
    __syncthreads();
    const float inv = 1.0f / (red[4] + red[5] + red[6] + red[7]);
    __bf16* prow = probs + (size_t)bp * Ss;
    prow[tid] = (__bf16)(e0 * inv);
    prow[tid + 256] = (__bf16)(e1 * inv);
}

// ---------------------------------------------------------------------------
// Generic bf16 MFMA GEMM, 64x64 block tile, 4 waves (2x2) x 32x32 wave tile.
// A row-major [rows][AK] bf16, Bt transposed [N][KB] bf16, fp32 accumulate.
// MODE 0: ctx = probs@Hi   (per-batch Bt=HiT)  epi: ctx_bf, (ctx*Hj)_bf
// MODE 1: mhid = relu(ctx@Wc + Hj@Wj + cxh@Wh + bv1)  (3 K-segments, s=1 from fp32 Hj)
// MODE 2: out = alpha*(mhid@Wv2 + bv2)
// ---------------------------------------------------------------------------
template<int MODE>
__global__ __launch_bounds__(256) void gemm_kernel(
    const __bf16* __restrict__ A, const __bf16* __restrict__ Bt,
    const float* __restrict__ Hjf, const float* __restrict__ bias,
    const float* __restrict__ alphap,
    __bf16* __restrict__ ob0, __bf16* __restrict__ ob1,
    float* __restrict__ of)
{
    constexpr int AK = (MODE == 0) ? 512 : 768;   // per-segment K
    constexpr int KB = (MODE == 1) ? 2304 : AK;   // Bt row length
    constexpr int NSEG = (MODE == 1) ? 3 : 1;

    const int tid = threadIdx.x;
    const int lane = tid & 63;
    const int wid = tid >> 6;
    const int col = lane & 15, g = lane >> 4;
    const int wm = wid >> 1, wn = wid & 1;
    const int bz = blockIdx.z;
    const int grow = ((MODE == 0) ? bz * Ss : 0) + blockIdx.x * 64 + wm * 32;
    const int n0 = blockIdx.y * 64 + wn * 32;
    const __bf16* Btb = (MODE == 0) ? Bt + (size_t)bz * (Hh * Ss) : Bt;

    f32x4 acc[2][2];
    #pragma unroll
    for (int mi = 0; mi < 2; ++mi)
        #pragma unroll
        for (int ni = 0; ni < 2; ++ni) acc[mi][ni] = (f32x4){0.f, 0.f, 0.f, 0.f};

    for (int s = 0; s < NSEG; ++s) {
        const __bf16* As = A + ((MODE == 1 && s == 2) ? (size_t)2048 * Hh : 0);
        #pragma unroll 2
        for (int kk = 0; kk < AK; kk += 32) {
            bf16x8 a[2], b[2];
            #pragma unroll
            for (int mi = 0; mi < 2; ++mi) {
                const int row = grow + mi * 16 + col;
                if (MODE == 1 && s == 1) {
                    const float* p = &Hjf[(size_t)row * Hh + kk + g * 8];
                    const float4 u = *(const float4*)p;
                    const float4 v = *(const float4*)(p + 4);
                    a[mi][0]=(__bf16)u.x; a[mi][1]=(__bf16)u.y;
                    a[mi][2]=(__bf16)u.z; a[mi][3]=(__bf16)u.w;
                    a[mi][4]=(__bf16)v.x; a[mi][5]=(__bf16)v.y;
                    a[mi][6]=(__bf16)v.z; a[mi][7]=(__bf16)v.w;
                } else {
                    a[mi] = *(const bf16x8*)&As[(size_t)row * AK + kk + g * 8];
                }
            }
            #pragma unroll
            for (int ni = 0; ni < 2; ++ni)
                b[ni] = *(const bf16x8*)&Btb[(size_t)(n0 + ni * 16 + col) * KB + s * Hh + kk + g * 8];
            #pragma unroll
            for (int mi = 0; mi < 2; ++mi)
                #pragma unroll
                for (int ni = 0; ni < 2; ++ni)
                    acc[mi][ni] = __builtin_amdgcn_mfma_f32_16x16x32_bf16(a[mi], b[ni], acc[mi][ni], 0, 0, 0);
        }
    }

    const float al = (MODE == 2) ? alphap[0] : 0.f;
    #pragma unroll
    for (int mi = 0; mi < 2; ++mi) {
        #pragma unroll
        for (int r = 0; r < 4; ++r) {
            const int row = grow + mi * 16 + g * 4 + r;
            #pragma unroll
            for (int ni = 0; ni < 2; ++ni) {
                const int cn = n0 + ni * 16 + col;
                const float v = acc[mi][ni][r];
                const size_t idx = (size_t)row * Hh + cn;
                if (MODE == 0) {
                    const float h = Hjf[idx];
                    ob0[idx] = (__bf16)v;
                    ob1[idx] = (__bf16)(v * h);
                } else if (MODE == 1) {
                    ob0[idx] = (__bf16)fmaxf(v + bias[cn], 0.f);
                } else {
                    of[idx] = al * (v + bias[cn]);
                }
            }
        }
    }
}

// ---------------------------------------------------------------------------
extern "C" void kernel_launch(void* const* d_in, const int* in_sizes, int n_in,
                              void* d_out, int out_size, void* d_ws, size_t ws_size,
                              hipStream_t stream)
{
    const float* Hj  = (const float*)d_in[0];
    const float* Hi  = (const float*)d_in[1];
    const float* Wpj = (const float*)d_in[2];
    const float* Wpi = (const float*)d_in[3];
    const float* Ws1 = (const float*)d_in[4];
    const float* bs1 = (const float*)d_in[5];
    const float* ws2 = (const float*)d_in[6];
    const float* bs2 = (const float*)d_in[7];
    const float* Wv1 = (const float*)d_in[8];
    const float* bv1 = (const float*)d_in[9];
    const float* Wv2 = (const float*)d_in[10];
    const float* bv2 = (const float*)d_in[11];
    const float* alpha = (const float*)d_in[12];
    const int* mask  = (const int*)d_in[13];

    // workspace layout (float units); lifetimes overlaid:
    //   R0: probs_bf (pair -> gemm0), later Wv2T (trans -> gemm2)
    //   R1: HiT (trans -> gemm0), later mhid_bf (gemm1 -> gemm2)
    float* ws = (float*)d_ws;
    float* Zj = ws;                                      // 2048*24
    float* Zi = Zj + (size_t)Bb * Ss * Dd;               // 2048*24
    float* R0f = Zi + (size_t)Bb * Ss * Dd;              // 524288 floats
    float* Abuf_f = R0f + 524288;                        // 2 segs x 786432 floats
    float* R1f = Abuf_f + 2 * 786432;                    // 786432 floats
    float* Wv1T_f = R1f + 786432;                        // 884736 floats
    // total: 3,866,624 floats = 15.5 MB

    __bf16* probs_bf = (__bf16*)R0f;                     // [2048][512]
    __bf16* Wv2T     = (__bf16*)R0f;                     // [768][768] (after gemm0)
    __bf16* ctx_bf   = (__bf16*)Abuf_f;                  // [2048][768]
    __bf16* cxh_bf   = ctx_bf + (size_t)2048 * Hh;       // [2048][768]
    __bf16* HiT      = (__bf16*)R1f;                     // [4][768][512]
    __bf16* mhid_bf  = (__bf16*)R1f;                     // [2048][768] (after gemm0)
    __bf16* Wv1T     = (__bf16*)Wv1T_f;                  // [768][2304]

    proj_kernel<<<dim3(Bb * Ss, 2), 256, 0, stream>>>(Hj, Hi, Wpj, Wpi, Zj, Zi);
    transpose_bf16_kernel<<<dim3(Hh / 32, Ss / 32, Bb), 256, 0, stream>>>(
        Hi, HiT, Ss, Hh, (long)Ss * Hh, (long)Hh * Ss);
    transpose_bf16_kernel<<<dim3(Hh / 32, 3 * Hh / 32, 1), 256, 0, stream>>>(
        Wv1, Wv1T, 3 * Hh, Oo, 0, 0);
    pair_kernel<<<dim3(Bb * Ss), 256, 0, stream>>>(Zj, Zi, Ws1, bs1, ws2, bs2, mask, probs_bf);
    gemm_kernel<0><<<dim3(Ss / 64, Hh / 64, Bb), 256, 0, stream>>>(
        probs_bf, HiT, Hj, nullptr, nullptr, ctx_bf, cxh_bf, nullptr);
    transpose_bf16_kernel<<<dim3(Hh / 32, Oo / 32, 1), 256, 0, stream>>>(
        Wv2, Wv2T, Oo, Hh, 0, 0);
    gemm_kernel<1><<<dim3(2048 / 64, Oo / 64, 1), 256, 0, stream>>>(
        ctx_bf, Wv1T, Hj, bv1, nullptr, mhid_bf, nullptr, nullptr);
    gemm_kernel<2><<<dim3(2048 / 64, Hh / 64, 1), 256, 0, stream>>>(
        mhid_bf, Wv2T, nullptr, bv2, alpha, nullptr, nullptr, (float*)d_out);
}

// Round 4
// 190.155 us; speedup vs baseline: 3.1273x; 1.3949x over previous
//
#include <hip/hip_runtime.h>
#include <hip/hip_bf16.h>

#define Bb 4
#define Ss 512
#define Hh 768
#define Dd 24
#define Mm 96
#define Oo 768

typedef __bf16 bf16x8 __attribute__((ext_vector_type(8)));
typedef float f32x4 __attribute__((ext_vector_type(4)));

// ---------------------------------------------------------------------------
// Kernel A: Zj = H_j @ Wpj, Zi = H_i @ Wpi   (B*S rows, H=768 -> D=24)
// ---------------------------------------------------------------------------
__global__ __launch_bounds__(256) void proj_kernel(
    const float* __restrict__ Hj, const float* __restrict__ Hi,
    const float* __restrict__ Wpj, const float* __restrict__ Wpi,
    float* __restrict__ Zj, float* __restrict__ Zi)
{
    const int row = blockIdx.x;
    const int which = blockIdx.y;
    const float* src = (which ? Hi : Hj) + (size_t)row * Hh;
    const float* W = which ? Wpi : Wpj;
    float* Z = which ? Zi : Zj;
    __shared__ float rowbuf[Hh];
    __shared__ float partial[8][Dd];
    const int tid = threadIdx.x;
    for (int i = tid; i < Hh; i += 256) rowbuf[i] = src[i];
    __syncthreads();
    if (tid < 192) {
        const int d = tid % Dd;
        const int c = tid / Dd;
        const int h0 = c * 96;
        float s = 0.f;
        #pragma unroll 4
        for (int h = h0; h < h0 + 96; ++h) s = fmaf(rowbuf[h], W[h * Dd + d], s);
        partial[c][d] = s;
    }
    __syncthreads();
    if (tid < Dd) {
        float s = 0.f;
        #pragma unroll
        for (int c = 0; c < 8; ++c) s += partial[c][tid];
        Z[(size_t)row * Dd + tid] = s;
    }
}

// ---------------------------------------------------------------------------
// Transpose + fp32->bf16:  dst[c][r] = bf16(src[r][c]),  tiles 32x32
// ---------------------------------------------------------------------------
__global__ __launch_bounds__(256) void transpose_bf16_kernel(
    const float* __restrict__ src, __bf16* __restrict__ dst,
    int R, int C, long sbatch, long dbatch)
{
    const float* s = src + (size_t)blockIdx.z * sbatch;
    __bf16* d = dst + (size_t)blockIdx.z * dbatch;
    __shared__ float t[32][33];
    const int x = threadIdx.x & 31, y = threadIdx.x >> 5;
    const int c0 = blockIdx.x * 32, r0 = blockIdx.y * 32;
    #pragma unroll
    for (int i = 0; i < 4; ++i)
        t[y + 8 * i][x] = s[(size_t)(r0 + y + 8 * i) * C + c0 + x];
    __syncthreads();
    #pragma unroll
    for (int i = 0; i < 4; ++i)
        d[(size_t)(c0 + y + 8 * i) * R + r0 + x] = (__bf16)t[x][y + 8 * i];
}

// ---------------------------------------------------------------------------
// Hj fp32 -> bf16 into segment 1 of concatenated A  ([2048][2304])
// ---------------------------------------------------------------------------
__global__ __launch_bounds__(256) void hjconv_kernel(
    const float* __restrict__ Hjf, __bf16* __restrict__ Ac)
{
    const int idx = blockIdx.x * 256 + threadIdx.x;  // 8-elem groups, 2048*96 total
    const int row = idx / 96, c8 = idx % 96;
    const float* s = Hjf + (size_t)row * Hh + c8 * 8;
    const float4 u = *(const float4*)s;
    const float4 v = *(const float4*)(s + 4);
    bf16x8 o;
    o[0]=(__bf16)u.x; o[1]=(__bf16)u.y; o[2]=(__bf16)u.z; o[3]=(__bf16)u.w;
    o[4]=(__bf16)v.x; o[5]=(__bf16)v.y; o[6]=(__bf16)v.z; o[7]=(__bf16)v.w;
    *(bf16x8*)&Ac[(size_t)row * 2304 + Hh + c8 * 8] = o;
}

// ---------------------------------------------------------------------------
// Kernel B (MFMA): per (b,p) block: logits over all 512 q + softmax -> bf16 probs
// ---------------------------------------------------------------------------
__global__ __launch_bounds__(256) void pair_kernel(
    const float* __restrict__ Zj, const float* __restrict__ Zi,
    const float* __restrict__ Ws1, const float* __restrict__ bs1,
    const float* __restrict__ ws2, const float* __restrict__ bs2p,
    const int* __restrict__ mask, __bf16* __restrict__ probs)
{
    const int bp = blockIdx.x;
    const int b  = bp >> 9;              // S = 512
    const int tid  = threadIdx.x;
    const int lane = tid & 63;
    const int wid  = tid >> 6;
    const int col  = lane & 15;
    const int g    = lane >> 4;

    __shared__ float zjall[Dd];
    __shared__ float rowadd[Mm];
    __shared__ float logitsl[Ss];
    __shared__ float red[8];

    if (tid < Dd) zjall[tid] = Zj[(size_t)bp * Dd + tid];
    __syncthreads();
    if (tid < Mm) {
        float s = bs1[tid];
        #pragma unroll
        for (int d = 0; d < Dd; ++d) s = fmaf(zjall[d], Ws1[d * Mm + tid], s);
        rowadd[tid] = s;
    }
    __syncthreads();

    float zj8[8];
    if (g < 3) {
        const float* zr = Zj + (size_t)bp * Dd + g * 8;
        const float4 u = *(const float4*)zr;
        const float4 v = *(const float4*)(zr + 4);
        zj8[0]=u.x; zj8[1]=u.y; zj8[2]=u.z; zj8[3]=u.w;
        zj8[4]=v.x; zj8[5]=v.y; zj8[6]=v.z; zj8[7]=v.w;
    } else {
        #pragma unroll
        for (int j = 0; j < 8; ++j) zj8[j] = 0.f;
    }

    bf16x8 bw[6][2];
    float ws2r[6];
    #pragma unroll
    for (int n = 0; n < 6; ++n) {
        const int m = n * 16 + col;
        ws2r[n] = ws2[m];
        bf16x8 b0, b1;
        if (g < 3) {
            #pragma unroll
            for (int j = 0; j < 8; ++j) {
                const int d = g * 8 + j;
                b0[j] = (__bf16)(fmaf(zj8[j], Ws1[(2 * Dd + d) * Mm + m],
                                      Ws1[(Dd + d) * Mm + m]));
                b1[j] = (__bf16)(Ws1[(3 * Dd + d) * Mm + m]);
            }
        } else {
            #pragma unroll
            for (int j = 0; j < 8; ++j) { b0[j] = (__bf16)0.f; b1[j] = (__bf16)0.f; }
            b0[0] = (__bf16)rowadd[m];
        }
        bw[n][0] = b0; bw[n][1] = b1;
    }

    const float* zib = Zi + (size_t)b * Ss * Dd;

    #pragma unroll 2
    for (int t = 0; t < 8; ++t) {
        const int q0 = wid * 128 + t * 16;
        bf16x8 a0, a1;
        if (g < 3) {
            const float* zr = zib + (size_t)(q0 + col) * Dd + g * 8;
            const float4 u = *(const float4*)zr;
            const float4 v = *(const float4*)(zr + 4);
            a0[0]=(__bf16)u.x; a0[1]=(__bf16)u.y; a0[2]=(__bf16)u.z; a0[3]=(__bf16)u.w;
            a0[4]=(__bf16)v.x; a0[5]=(__bf16)v.y; a0[6]=(__bf16)v.z; a0[7]=(__bf16)v.w;
            a1[0]=(__bf16)fabsf(zj8[0]-u.x); a1[1]=(__bf16)fabsf(zj8[1]-u.y);
            a1[2]=(__bf16)fabsf(zj8[2]-u.z); a1[3]=(__bf16)fabsf(zj8[3]-u.w);
            a1[4]=(__bf16)fabsf(zj8[4]-v.x); a1[5]=(__bf16)fabsf(zj8[5]-v.y);
            a1[6]=(__bf16)fabsf(zj8[6]-v.z); a1[7]=(__bf16)fabsf(zj8[7]-v.w);
        } else {
            #pragma unroll
            for (int j = 0; j < 8; ++j) { a0[j] = (__bf16)0.f; a1[j] = (__bf16)0.f; }
            a0[0] = (__bf16)1.0f;
        }

        f32x4 acc[6];
        #pragma unroll
        for (int n = 0; n < 6; ++n) acc[n] = (f32x4){0.f, 0.f, 0.f, 0.f};
        #pragma unroll
        for (int n = 0; n < 6; ++n) {
            acc[n] = __builtin_amdgcn_mfma_f32_16x16x32_bf16(a0, bw[n][0], acc[n], 0, 0, 0);
            acc[n] = __builtin_amdgcn_mfma_f32_16x16x32_bf16(a1, bw[n][1], acc[n], 0, 0, 0);
        }

        float lsum[4] = {0.f, 0.f, 0.f, 0.f};
        #pragma unroll
        for (int n = 0; n < 6; ++n)
            #pragma unroll
            for (int r = 0; r < 4; ++r)
                lsum[r] = fmaf(fmaxf(acc[n][r], 0.f), ws2r[n], lsum[r]);
        #pragma unroll
        for (int off = 1; off <= 8; off <<= 1) {
            #pragma unroll
            for (int r = 0; r < 4; ++r) lsum[r] += __shfl_xor(lsum[r], off);
        }
        if (col == 0) {
            float4 o = {lsum[0], lsum[1], lsum[2], lsum[3]};
            *(float4*)&logitsl[q0 + g * 4] = o;
        }
    }
    __syncthreads();

    const float bs2v = bs2p[0];
    const int* mrow = mask + (size_t)b * Ss;
    float l0 = logitsl[tid]       + bs2v + (1.0f - (float)mrow[tid])       * (-3.402823466e+38f);
    float l1 = logitsl[tid + 256] + bs2v + (1.0f - (float)mrow[tid + 256]) * (-3.402823466e+38f);
    float vmax = fmaxf(l0, l1);
    #pragma unroll
    for (int off = 32; off > 0; off >>= 1) vmax = fmaxf(vmax, __shfl_xor(vmax, off));
    if (lane == 0) red[wid] = vmax;
    __syncthreads();
    const float mx = fmaxf(fmaxf(red[0], red[1]), fmaxf(red[2], red[3]));
    const float e0 = __expf(l0 - mx);
    const float e1 = __expf(l1 - mx);
    float vs = e0 + e1;
    #pragma unroll
    for (int off = 32; off > 0; off >>= 1) vs += __shfl_xor(vs, off);
    if (lane == 0) red[4 + wid] = vs;
    __syncthreads();
    const float inv = 1.0f / (red[4] + red[5] + red[6] + red[7]);
    __bf16* prow = probs + (size_t)bp * Ss;
    prow[tid] = (__bf16)(e0 * inv);
    prow[tid + 256] = (__bf16)(e1 * inv);
}

// ---------------------------------------------------------------------------
// bf16 MFMA GEMM, 64x64 block tile, BK=64, LDS single-buffer (padded) with
// register prefetch of the next K-slab. 4 waves (2x2), wave tile 32x32.
// A [M][K] bf16 k-contig;  Bt [N][K] bf16 k-contig.
// MODE 0: ctx = probs@HiT(batch)  -> write A_concat seg0 (ctx) & seg2 (ctx*Hj)
// MODE 1: mhid = relu(Acat@Wv1T + bv1) -> bf16
// MODE 2: out  = alpha*(mhid@Wv2T + bv2) -> fp32
// ---------------------------------------------------------------------------
template<int MODE>
__global__ __launch_bounds__(256) void gemm_kernel(
    const __bf16* __restrict__ A, const __bf16* __restrict__ Bt,
    const float* __restrict__ Hjf, const float* __restrict__ bias,
    const float* __restrict__ alphap,
    __bf16* __restrict__ obf, float* __restrict__ of)
{
    constexpr int K = (MODE == 0) ? 512 : (MODE == 1) ? 2304 : 768;
    constexpr int NIT = K / 64;
    constexpr int LDT = 72;               // padded LDS row stride (elems)

    __shared__ __bf16 As[64 * LDT];
    __shared__ __bf16 Bs[64 * LDT];

    const int tid = threadIdx.x;
    const int lane = tid & 63;
    const int wid = tid >> 6;
    const int col = lane & 15, g = lane >> 4;
    const int wm = wid >> 1, wn = wid & 1;
    const int r0 = blockIdx.x * 64;
    const int n0 = blockIdx.y * 64;
    const __bf16* Btb = (MODE == 0) ? Bt + (size_t)(r0 >> 9) * (Hh * Ss) : Bt;

    // staging: thread t handles row t/4, two adjacent 16B chunks (2*(t&3), +1)
    const int srow = tid >> 2;
    const int sc8  = (tid & 3) * 16;      // elem offset of chunk pair
    const __bf16* ag = A   + (size_t)(r0 + srow) * K + sc8;
    const __bf16* bg = Btb + (size_t)(n0 + srow) * K + sc8;
    __bf16* asl = &As[srow * LDT + sc8];
    __bf16* bsl = &Bs[srow * LDT + sc8];

    bf16x8 ra0 = *(const bf16x8*)(ag);
    bf16x8 ra1 = *(const bf16x8*)(ag + 8);
    bf16x8 rb0 = *(const bf16x8*)(bg);
    bf16x8 rb1 = *(const bf16x8*)(bg + 8);

    f32x4 acc[2][2];
    #pragma unroll
    for (int mi = 0; mi < 2; ++mi)
        #pragma unroll
        for (int ni = 0; ni < 2; ++ni) acc[mi][ni] = (f32x4){0.f, 0.f, 0.f, 0.f};

    for (int it = 0; it < NIT; ++it) {
        __syncthreads();
        *(bf16x8*)(asl)     = ra0;
        *(bf16x8*)(asl + 8) = ra1;
        *(bf16x8*)(bsl)     = rb0;
        *(bf16x8*)(bsl + 8) = rb1;
        __syncthreads();
        if (it + 1 < NIT) {
            const int kk = (it + 1) * 64;
            ra0 = *(const bf16x8*)(ag + kk);
            ra1 = *(const bf16x8*)(ag + kk + 8);
            rb0 = *(const bf16x8*)(bg + kk);
            rb1 = *(const bf16x8*)(bg + kk + 8);
        }
        #pragma unroll
        for (int h = 0; h < 2; ++h) {
            bf16x8 a0 = *(const bf16x8*)&As[(wm * 32 + col)      * LDT + h * 32 + g * 8];
            bf16x8 a1 = *(const bf16x8*)&As[(wm * 32 + 16 + col) * LDT + h * 32 + g * 8];
            bf16x8 b0 = *(const bf16x8*)&Bs[(wn * 32 + col)      * LDT + h * 32 + g * 8];
            bf16x8 b1 = *(const bf16x8*)&Bs[(wn * 32 + 16 + col) * LDT + h * 32 + g * 8];
            acc[0][0] = __builtin_amdgcn_mfma_f32_16x16x32_bf16(a0, b0, acc[0][0], 0, 0, 0);
            acc[0][1] = __builtin_amdgcn_mfma_f32_16x16x32_bf16(a0, b1, acc[0][1], 0, 0, 0);
            acc[1][0] = __builtin_amdgcn_mfma_f32_16x16x32_bf16(a1, b0, acc[1][0], 0, 0, 0);
            acc[1][1] = __builtin_amdgcn_mfma_f32_16x16x32_bf16(a1, b1, acc[1][1], 0, 0, 0);
        }
    }

    const float al = (MODE == 2) ? alphap[0] : 0.f;
    #pragma unroll
    for (int mi = 0; mi < 2; ++mi) {
        #pragma unroll
        for (int r = 0; r < 4; ++r) {
            const int row = r0 + wm * 32 + mi * 16 + g * 4 + r;
            #pragma unroll
            for (int ni = 0; ni < 2; ++ni) {
                const int cn = n0 + wn * 32 + ni * 16 + col;
                const float v = acc[mi][ni][r];
                if (MODE == 0) {
                    const float hjv = Hjf[(size_t)row * Hh + cn];
                    obf[(size_t)row * 2304 + cn] = (__bf16)v;
                    obf[(size_t)row * 2304 + 1536 + cn] = (__bf16)(v * hjv);
                } else if (MODE == 1) {
                    obf[(size_t)row * Oo + cn] = (__bf16)fmaxf(v + bias[cn], 0.f);
                } else {
                    of[(size_t)row * Hh + cn] = al * (v + bias[cn]);
                }
            }
        }
    }
}

// ---------------------------------------------------------------------------
extern "C" void kernel_launch(void* const* d_in, const int* in_sizes, int n_in,
                              void* d_out, int out_size, void* d_ws, size_t ws_size,
                              hipStream_t stream)
{
    const float* Hj  = (const float*)d_in[0];
    const float* Hi  = (const float*)d_in[1];
    const float* Wpj = (const float*)d_in[2];
    const float* Wpi = (const float*)d_in[3];
    const float* Ws1 = (const float*)d_in[4];
    const float* bs1 = (const float*)d_in[5];
    const float* ws2 = (const float*)d_in[6];
    const float* bs2 = (const float*)d_in[7];
    const float* Wv1 = (const float*)d_in[8];
    const float* bv1 = (const float*)d_in[9];
    const float* Wv2 = (const float*)d_in[10];
    const float* bv2 = (const float*)d_in[11];
    const float* alpha = (const float*)d_in[12];
    const int* mask  = (const int*)d_in[13];

    // workspace (float units), overlays:
    //   R0: probs_bf (pair->gemm0), later Wv2T (after gemm0)
    //   R1: HiT (->gemm0), later mhid_bf (gemm1->gemm2)
    float* ws = (float*)d_ws;
    float* Zj = ws;                                      // 49152
    float* Zi = Zj + 49152;                              // 49152
    float* R0f = Zi + 49152;                             // 524288
    float* R1f = R0f + 524288;                           // 786432
    float* Acat_f = R1f + 786432;                        // 2359296
    float* Wv1T_f = Acat_f + 2359296;                    // 884736
    // total 4,653,056 floats = 18.6 MB

    __bf16* probs_bf = (__bf16*)R0f;                     // [2048][512]
    __bf16* Wv2T     = (__bf16*)R0f;                     // [768][768]
    __bf16* HiT      = (__bf16*)R1f;                     // [4][768][512]
    __bf16* mhid_bf  = (__bf16*)R1f;                     // [2048][768]
    __bf16* Acat     = (__bf16*)Acat_f;                  // [2048][2304]
    __bf16* Wv1T     = (__bf16*)Wv1T_f;                  // [768][2304]

    proj_kernel<<<dim3(Bb * Ss, 2), 256, 0, stream>>>(Hj, Hi, Wpj, Wpi, Zj, Zi);
    transpose_bf16_kernel<<<dim3(Hh / 32, Ss / 32, Bb), 256, 0, stream>>>(
        Hi, HiT, Ss, Hh, (long)Ss * Hh, (long)Hh * Ss);
    transpose_bf16_kernel<<<dim3(Oo / 32, 3 * Hh / 32, 1), 256, 0, stream>>>(
        Wv1, Wv1T, 3 * Hh, Oo, 0, 0);
    hjconv_kernel<<<dim3(768), 256, 0, stream>>>(Hj, Acat);
    pair_kernel<<<dim3(Bb * Ss), 256, 0, stream>>>(Zj, Zi, Ws1, bs1, ws2, bs2, mask, probs_bf);
    gemm_kernel<0><<<dim3(2048 / 64, Hh / 64), 256, 0, stream>>>(
        probs_bf, HiT, Hj, nullptr, nullptr, Acat, nullptr);
    transpose_bf16_kernel<<<dim3(Hh / 32, Oo / 32, 1), 256, 0, stream>>>(
        Wv2, Wv2T, Oo, Hh, 0, 0);
    gemm_kernel<1><<<dim3(2048 / 64, Oo / 64), 256, 0, stream>>>(
        Acat, Wv1T, nullptr, bv1, nullptr, mhid_bf, nullptr);
    gemm_kernel<2><<<dim3(2048 / 64, Hh / 64), 256, 0, stream>>>(
        mhid_bf, Wv2T, nullptr, bv2, alpha, nullptr, (float*)d_out);
}